// Round 6
// baseline (318.962 us; speedup 1.0000x reference)
//
#include <hip/hip_runtime.h>
#include <math.h>

#define BB 32
#define NN 8192
#define DD 128
#define KK 64

// ---------------- Kernel 1: m1c = normalize(normalize(modal1)) ----------------
__global__ __launch_bounds__(128) void norm_m1_kernel(const float* __restrict__ modal1,
                                                      float* __restrict__ m1c) {
    int b = blockIdx.x;
    int d = threadIdx.x;              // 128 threads = 2 waves
    int lane = d & 63, wid = d >> 6;
    float x = modal1[b * DD + d];

    __shared__ float red[2];
    float s = x * x;
    #pragma unroll
    for (int off = 32; off > 0; off >>= 1) s += __shfl_xor(s, off);
    if (lane == 0) red[wid] = s;
    __syncthreads();
    float s1 = red[0] + red[1];
    float inv1 = 1.0f / fmaxf(sqrtf(s1), 1e-12f);
    float m1 = x * inv1;
    __syncthreads();

    float s2p = m1 * m1;
    #pragma unroll
    for (int off = 32; off > 0; off >>= 1) s2p += __shfl_xor(s2p, off);
    if (lane == 0) red[wid] = s2p;
    __syncthreads();
    float s2 = red[0] + red[1];
    float inv2 = 1.0f / fmaxf(sqrtf(s2), 1e-8f);
    m1c[b * DD + d] = m1 * inv2;
}

// ---------------- Kernel 2: cos_sim[b,n], inv_norm[b,n] ----------------
// 2 rows per wave: lanes 0-31 -> row 2p, lanes 32-63 -> row 2p+1.
// Each lane loads float4 (16B) -> 1KB per wave per pair, fully coalesced.
__global__ __launch_bounds__(256) void cos_kernel(const float* __restrict__ modal2,
                                                  const float* __restrict__ m1c,
                                                  float* __restrict__ cos_out,
                                                  float* __restrict__ inv_out) {
    int lane = threadIdx.x & 63;
    int sub = lane >> 5;              // which row of the pair
    int c = lane & 31;                // float4 slot within row
    int gwave = (blockIdx.x * blockDim.x + threadIdx.x) >> 6;
    int nwaves = (gridDim.x * blockDim.x) >> 6;
    const int npairs = BB * NN / 2;

    for (int p = gwave; p < npairs; p += nwaves) {
        int r = p * 2 + sub;
        int b = p >> 12;              // (2p)>>13 == p>>12; pairs never cross batch
        const float4 xv = *reinterpret_cast<const float4*>(modal2 + (size_t)r * DD + c * 4);
        const float4 mv = *reinterpret_cast<const float4*>(m1c + b * DD + c * 4);
        float ss = xv.x * xv.x + xv.y * xv.y + xv.z * xv.z + xv.w * xv.w;
        float dd = xv.x * mv.x + xv.y * mv.y + xv.z * mv.z + xv.w * mv.w;
        #pragma unroll
        for (int off = 16; off > 0; off >>= 1) {   // stays within 32-lane group
            ss += __shfl_xor(ss, off);
            dd += __shfl_xor(dd, off);
        }
        if (c == 0) {
            float inv1 = 1.0f / fmaxf(sqrtf(ss), 1e-12f);       // first normalize (eps 1e-12)
            float s2 = ss * inv1 * inv1;                         // ||m2||^2 after norm
            float inv2 = 1.0f / fmaxf(sqrtf(s2), 1e-8f);         // cosine_similarity renorm
            cos_out[r] = dd * inv1 * inv2;
            inv_out[r] = inv1;
        }
    }
}

// ---------------- Kernel 3: per-b top-K (ordered) + softmax-weighted gather ----------------
__device__ __forceinline__ unsigned long long packkey(float f, int n) {
    unsigned u = __float_as_uint(f);
    u = (u & 0x80000000u) ? ~u : (u | 0x80000000u);   // monotone-unsigned float
    return ((unsigned long long)u << 32) | (unsigned)(NN - 1 - n);  // ties -> smaller n wins max
}

// count of elements in descending-sorted unique list[64] strictly greater than key.
// NOTE: 7 iterations required — interval 64 needs 7 halvings to reach lo==hi
// (6 leaves interval length 1 -> off-by-one -> duplicate ranks -> uninitialized
// topk_idx slot -> OOB gather -> the round-3/4 device fault).
__device__ __forceinline__ int count_greater(const unsigned long long* __restrict__ list,
                                             unsigned long long key) {
    int lo = 0, hi = KK;
    #pragma unroll
    for (int it = 0; it < 7; ++it) {
        int mid = (lo + hi) >> 1;
        if (list[mid] > key) lo = mid + 1; else hi = mid;
    }
    return lo;
}

__global__ __launch_bounds__(256) void topk_kernel(const float* __restrict__ modal2,
                                                   const float* __restrict__ cos_sim,
                                                   const float* __restrict__ inv_norm,
                                                   const float* __restrict__ weights,
                                                   float* __restrict__ out) {
    int b = blockIdx.x;
    int tid = threadIdx.x;
    int lane = tid & 63, wid = tid >> 6;     // 4 waves

    __shared__ __align__(16) float vals[NN];  // 32 KB, 16B-aligned for float4/b128 access
    __shared__ unsigned long long skey[4][KK];
    __shared__ int topk_idx[KK];
    __shared__ float coef[KK];
    __shared__ __align__(16) float partial[DD];

    // coalesced float4 load of the cos row into LDS
    const float* crow = cos_sim + (size_t)b * NN;
    #pragma unroll
    for (int j = 0; j < NN / 4 / 256; ++j) {
        int i = (tid + j * 256) * 4;
        *reinterpret_cast<float4*>(&vals[i]) = *reinterpret_cast<const float4*>(&crow[i]);
    }
    __syncthreads();

    // ---- wave-local top-64 over segment [wid*2048, (wid+1)*2048), shuffle-only ----
    const int base = wid * (NN / 4);
    unsigned long long best = 0ull;
    #pragma unroll
    for (int j = 0; j < NN / 4 / 64; ++j) {      // 32 slots per lane
        int n = base + lane + 64 * j;
        unsigned long long kk2 = packkey(vals[n], n);
        if (kk2 > best) best = kk2;
    }
    for (int k = 0; k < KK; ++k) {
        unsigned long long m = best;
        #pragma unroll
        for (int off = 32; off > 0; off >>= 1) {
            unsigned long long o = __shfl_xor(m, off);
            if (o > m) m = o;
        }
        if (lane == k) skey[wid][k] = m;
        if (best == m) {                          // unique winner (index embedded)
            int widx = NN - 1 - (int)(m & 0xffffffffu);
            vals[widx] = -INFINITY;               // own segment, own lane: no barrier needed
            best = 0ull;
            #pragma unroll
            for (int j = 0; j < NN / 4 / 64; ++j) {
                int n = base + lane + 64 * j;
                unsigned long long kk2 = packkey(vals[n], n);
                if (kk2 > best) best = kk2;
            }
        }
    }
    __syncthreads();

    // ---- parallel rank-merge of 4 descending lists: thread (wid,lane) ranks its key ----
    // Keys are globally unique (index embedded) -> ranks are a permutation of 0..255,
    // so slots 0..63 of topk_idx are each written exactly once.
    {
        unsigned long long key = skey[wid][lane];
        int rank = lane;                          // position in own list
        #pragma unroll
        for (int w = 1; w < 4; ++w)
            rank += count_greater(skey[(wid + w) & 3], key);
        if (rank < KK) topk_idx[rank] = NN - 1 - (int)(key & 0xffffffffu);
    }
    __syncthreads();

    // ---- softmax over weights[b,:] on wave 0; coef[k] = w[k] * inv_norm[b, idx[k]] ----
    if (wid == 0) {
        float wv = weights[b * KK + lane];
        float mx = wv;
        #pragma unroll
        for (int off = 32; off > 0; off >>= 1) mx = fmaxf(mx, __shfl_xor(mx, off));
        float e = expf(wv - mx);
        float s = e;
        #pragma unroll
        for (int off = 32; off > 0; off >>= 1) s += __shfl_xor(s, off);
        float w = e / s;
        int idx = topk_idx[lane];
        coef[lane] = w * inv_norm[(size_t)b * NN + idx];
    }
    __syncthreads();

    // ---- out[b,d] = sum_k coef[k] * modal2[b, idx[k], d], split over 2 k-halves ----
    {
        int d = tid & (DD - 1);
        int half = tid >> 7;                      // 0 or 1
        const float* bbase = modal2 + (size_t)b * NN * DD;
        float acc = 0.f;
        #pragma unroll
        for (int k = 0; k < KK / 2; ++k) {
            int kk2 = half * (KK / 2) + k;
            acc += coef[kk2] * bbase[(size_t)topk_idx[kk2] * DD + d];
        }
        if (half == 0) partial[d] = acc;
        __syncthreads();
        if (half == 1) out[b * DD + d] = partial[d] + acc;
    }
}

extern "C" void kernel_launch(void* const* d_in, const int* in_sizes, int n_in,
                              void* d_out, int out_size, void* d_ws, size_t ws_size,
                              hipStream_t stream) {
    const float* modal1  = (const float*)d_in[0];
    const float* modal2  = (const float*)d_in[1];
    const float* weights = (const float*)d_in[2];
    float* out = (float*)d_out;

    char* ws = (char*)d_ws;
    float* m1c      = (float*)ws;                       // 32*128*4 = 16 KB
    float* cos_sim  = (float*)(ws + 16384);             // 32*8192*4 = 1 MB
    float* inv_norm = (float*)(ws + 16384 + BB * NN * 4);

    norm_m1_kernel<<<BB, 128, 0, stream>>>(modal1, m1c);
    cos_kernel<<<2048, 256, 0, stream>>>(modal2, m1c, cos_sim, inv_norm);
    topk_kernel<<<BB, 256, 0, stream>>>(modal2, cos_sim, inv_norm, weights, out);
}

// Round 7
// 205.760 us; speedup vs baseline: 1.5502x; 1.5502x over previous
//
#include <hip/hip_runtime.h>
#include <math.h>

#define BB 32
#define NN 8192
#define DD 128
#define KK 64
#define NBINS 4096
#define CAP 2048

__device__ __forceinline__ unsigned monokey(float f) {
    unsigned u = __float_as_uint(f);
    return (u & 0x80000000u) ? ~u : (u | 0x80000000u);   // monotone-unsigned float
}

// ---------------- Kernel 1: fused m1-normalize + cosine + inv_norm ----------------
// Block = 64 contiguous row-pairs of one batch (2048 blocks total, b = blk>>6).
// Each wave owns 16 contiguous pairs; lanes 0-31 row 2p, 32-63 row 2p+1;
// lane holds one float4 of the row. m1c fragment hoisted to registers.
__global__ __launch_bounds__(256) void cos_kernel(const float* __restrict__ modal2,
                                                  const float* __restrict__ modal1,
                                                  float* __restrict__ cos_out,
                                                  float* __restrict__ inv_out) {
    const int tid = threadIdx.x;
    const int lane = tid & 63, wid = tid >> 6;
    const int b = blockIdx.x >> 6;                 // 64 blocks per batch

    __shared__ __align__(16) float m1s[DD];
    __shared__ float red[2];

    // double-normalized modal1 row -> LDS (threads 0..127; s2 = s1*inv1^2 algebraically)
    float x = 0.f;
    if (tid < DD) {
        x = modal1[b * DD + tid];
        float s = x * x;
        #pragma unroll
        for (int off = 32; off > 0; off >>= 1) s += __shfl_xor(s, off);
        if (lane == 0) red[wid] = s;               // wid 0/1 only
    }
    __syncthreads();
    if (tid < DD) {
        float s1 = red[0] + red[1];
        float inv1 = 1.0f / fmaxf(sqrtf(s1), 1e-12f);
        float s2 = s1 * inv1 * inv1;
        float inv2 = 1.0f / fmaxf(sqrtf(s2), 1e-8f);
        m1s[tid] = x * (inv1 * inv2);
    }
    __syncthreads();

    const int sub = lane >> 5;                     // row within pair
    const int c = lane & 31;                       // float4 slot
    const float4 mv = *reinterpret_cast<const float4*>(&m1s[c * 4]);
    const int pair0 = blockIdx.x * 64 + wid * 16;

    #pragma unroll 4
    for (int i = 0; i < 16; ++i) {
        int r = (pair0 + i) * 2 + sub;
        const float4 xv = *reinterpret_cast<const float4*>(modal2 + (size_t)r * DD + c * 4);
        float ss = xv.x * xv.x + xv.y * xv.y + xv.z * xv.z + xv.w * xv.w;
        float dd = xv.x * mv.x + xv.y * mv.y + xv.z * mv.z + xv.w * mv.w;
        #pragma unroll
        for (int off = 16; off > 0; off >>= 1) {   // within 32-lane group
            ss += __shfl_xor(ss, off);
            dd += __shfl_xor(dd, off);
        }
        if (c == 0) {
            float inv1 = 1.0f / fmaxf(sqrtf(ss), 1e-12f);   // F.normalize eps
            float s2 = ss * inv1 * inv1;                     // ||m2||^2 after norm
            float inv2 = 1.0f / fmaxf(sqrtf(s2), 1e-8f);     // cosine_similarity renorm
            cos_out[r] = dd * inv1 * inv2;
            inv_out[r] = inv1;
        }
    }
}

// ---------------- Kernel 2: histogram-select top-K + softmax-weighted gather ----------------
__global__ __launch_bounds__(256) void topk_kernel(const float* __restrict__ modal2,
                                                   const float* __restrict__ cos_sim,
                                                   const float* __restrict__ inv_norm,
                                                   const float* __restrict__ weights,
                                                   float* __restrict__ out) {
    const int b = blockIdx.x;
    const int tid = threadIdx.x;
    const int lane = tid & 63, wid = tid >> 6;

    __shared__ __align__(16) unsigned keys[NN];          // 32 KB monotone keys
    __shared__ unsigned bins[NBINS];                     // 16 KB
    __shared__ unsigned long long cand[CAP];             // 16 KB
    __shared__ int cnt, thr_sh;
    __shared__ int topk_idx[KK];
    __shared__ float coef[KK];
    __shared__ __align__(16) float partial[DD];

    // zero bins + cnt; load row -> monotone keys (float4/uint4)
    for (int j = tid; j < NBINS; j += 256) bins[j] = 0u;
    if (tid == 0) cnt = 0;
    const float* crow = cos_sim + (size_t)b * NN;
    #pragma unroll
    for (int j = 0; j < NN / 4 / 256; ++j) {
        int i = (tid + j * 256) * 4;
        float4 v = *reinterpret_cast<const float4*>(&crow[i]);
        uint4 kv = make_uint4(monokey(v.x), monokey(v.y), monokey(v.z), monokey(v.w));
        *reinterpret_cast<uint4*>(&keys[i]) = kv;
    }
    __syncthreads();

    // 12-bit histogram via LDS atomics
    #pragma unroll
    for (int j = 0; j < NN / 256; ++j) {
        int n = tid + j * 256;
        atomicAdd(&bins[keys[n] >> 20], 1u);
    }
    __syncthreads();

    // threshold bin: max t with suffix-count(bins >= t) >= KK (wave 0 only)
    if (tid < 64) {
        unsigned csum = 0;
        #pragma unroll
        for (int j = 0; j < NBINS / 64; ++j) csum += bins[tid * (NBINS / 64) + j];
        unsigned T = csum;                                  // suffix-scan chunk sums
        #pragma unroll
        for (int off = 1; off < 64; off <<= 1) {
            unsigned t2 = __shfl_down(T, off);
            if (tid + off < 64) T += t2;
        }
        unsigned long long mk = __ballot(T >= KK);          // prefix of set bits
        int Cs = 63 - __builtin_clzll(mk);
        unsigned above = (Cs < 63) ? __shfl(T, Cs + 1) : 0u;
        unsigned W = bins[Cs * (NBINS / 64) + tid];         // suffix-scan within chunk
        #pragma unroll
        for (int off = 1; off < 64; off <<= 1) {
            unsigned t2 = __shfl_down(W, off);
            if (tid + off < 64) W += t2;
        }
        unsigned long long mk2 = __ballot(above + W >= KK);
        int off2 = 63 - __builtin_clzll(mk2);
        if (tid == 0) thr_sh = Cs * (NBINS / 64) + off2;
    }
    __syncthreads();
    const int thr = thr_sh;

    // compact candidates (bin >= thr): typically ~K + ~30 for continuous data
    #pragma unroll
    for (int j = 0; j < NN / 256; ++j) {
        int n = tid + j * 256;
        unsigned k = keys[n];
        if ((int)(k >> 20) >= thr) {
            int pos = atomicAdd(&cnt, 1);
            if (pos < CAP)
                cand[pos] = ((unsigned long long)k << 32) | (unsigned)(NN - 1 - n);
        }
    }
    __syncthreads();
    const int M = min(cnt, CAP);                            // M >= KK by construction

    // exact ordered ranks: keys unique (index embedded) -> ranks distinct;
    // tie on value -> larger (NN-1-n) first = smaller n first, matching lax.top_k
    for (int i = tid; i < M; i += 256) {
        unsigned long long key = cand[i];
        int r = 0;
        for (int j = 0; j < M; ++j) r += (cand[j] > key);
        if (r < KK) topk_idx[r] = NN - 1 - (int)(key & 0xffffffffu);
    }
    __syncthreads();

    // softmax over weights[b,:] on wave 0; coef[k] = w[k] * inv_norm[b, idx[k]]
    if (wid == 0) {
        float wv = weights[b * KK + lane];
        float mx = wv;
        #pragma unroll
        for (int off = 32; off > 0; off >>= 1) mx = fmaxf(mx, __shfl_xor(mx, off));
        float e = expf(wv - mx);
        float s = e;
        #pragma unroll
        for (int off = 32; off > 0; off >>= 1) s += __shfl_xor(s, off);
        float w = e / s;
        int idx = topk_idx[lane];
        coef[lane] = w * inv_norm[(size_t)b * NN + idx];
    }
    __syncthreads();

    // out[b,d] = sum_k coef[k] * modal2[b, idx[k], d], split over 2 k-halves
    {
        int d = tid & (DD - 1);
        int half = tid >> 7;
        const float* bbase = modal2 + (size_t)b * NN * DD;
        float acc = 0.f;
        #pragma unroll
        for (int k = 0; k < KK / 2; ++k) {
            int kk2 = half * (KK / 2) + k;
            acc += coef[kk2] * bbase[(size_t)topk_idx[kk2] * DD + d];
        }
        if (half == 0) partial[d] = acc;
        __syncthreads();
        if (half == 1) out[b * DD + d] = partial[d] + acc;
    }
}

extern "C" void kernel_launch(void* const* d_in, const int* in_sizes, int n_in,
                              void* d_out, int out_size, void* d_ws, size_t ws_size,
                              hipStream_t stream) {
    const float* modal1  = (const float*)d_in[0];
    const float* modal2  = (const float*)d_in[1];
    const float* weights = (const float*)d_in[2];
    float* out = (float*)d_out;

    char* ws = (char*)d_ws;
    float* cos_sim  = (float*)ws;                        // 32*8192*4 = 1 MB
    float* inv_norm = (float*)(ws + (size_t)BB * NN * 4);

    cos_kernel<<<2048, 256, 0, stream>>>(modal2, modal1, cos_sim, inv_norm);
    topk_kernel<<<BB, 256, 0, stream>>>(modal2, cos_sim, inv_norm, weights, out);
}